// Round 1
// baseline (1212.734 us; speedup 1.0000x reference)
//
#include <hip/hip_runtime.h>
#include <hip/hip_bf16.h>

typedef unsigned short ushort_t;
typedef __attribute__((ext_vector_type(8))) short short8;
typedef __attribute__((ext_vector_type(8))) unsigned short ushort8;
typedef __attribute__((ext_vector_type(4))) unsigned short ushort4v;
typedef __attribute__((ext_vector_type(4))) float floatx4;
typedef __attribute__((ext_vector_type(4))) float f32x4;

#define DEVFN static __device__ __forceinline__

// round-to-nearest-even f32 -> bf16 (finite inputs only)
DEVFN ushort_t f2bf(float f) {
    union { float f; unsigned u; } v; v.f = f;
    unsigned r = v.u + 0x7fffu + ((v.u >> 16) & 1u);
    return (ushort_t)(r >> 16);
}
DEVFN float bf2f(ushort_t b) {
    union { unsigned u; float f; } v; v.u = ((unsigned)b) << 16; return v.f;
}

// async global->LDS, 16B per lane; lds dest must be wave-uniform base
DEVFN void gll16(const void* g, void* l) {
    __builtin_amdgcn_global_load_lds(
        (const __attribute__((address_space(1))) unsigned int*)g,
        (__attribute__((address_space(3))) unsigned int*)l, 16, 0, 0);
}

// ---------------- prep: split fp32 -> bf16 hi/lo ----------------
__global__ __launch_bounds__(256) void split_f32(
    const float* __restrict__ in, ushort_t* __restrict__ h,
    ushort_t* __restrict__ l, int n4)
{
    int i = blockIdx.x * 256 + threadIdx.x;
    if (i >= n4) return;
    floatx4 v = ((const floatx4*)in)[i];
    ushort4v H, L;
#pragma unroll
    for (int j = 0; j < 4; j++) {
        ushort_t hh = f2bf(v[j]);
        H[j] = hh;
        L[j] = f2bf(v[j] - bf2f(hh));
    }
    ((ushort4v*)h)[i] = H;
    ((ushort4v*)l)[i] = L;
}

// ---------------- prep: srcT[b][d][s] = bf16(source[s][b][d]) ----------------
__global__ __launch_bounds__(256) void transpose_src_k(
    const float* __restrict__ src, ushort_t* __restrict__ srcT)
{
    __shared__ float tile[32][33];
    int s0 = blockIdx.x << 5, d0 = blockIdx.y << 5, b = blockIdx.z;
    int t = threadIdx.x;
    int si = t >> 3, dj = (t & 7) << 2;
    floatx4 v = *(const floatx4*)&src[((size_t)(s0 + si) * 32 + b) * 1024 + d0 + dj];
    tile[si][dj + 0] = v[0]; tile[si][dj + 1] = v[1];
    tile[si][dj + 2] = v[2]; tile[si][dj + 3] = v[3];
    __syncthreads();
    int di = t >> 3, sj = (t & 7) << 2;
    ushort4v o;
#pragma unroll
    for (int q = 0; q < 4; q++) o[q] = f2bf(tile[sj + q][di]);
    *(ushort4v*)&srcT[((size_t)b * 1024 + d0 + di) * 1024 + s0 + sj] = o;
}

// ---------------- projection GEMM: C(MxN) = X(fp32, MxK) * W^T(NxK, split bf16) ----------------
// 3-pass split emulation; epilogue writes split bf16 (Ch, Cl).
__global__ __launch_bounds__(256, 2) void gemm_proj(
    const float* __restrict__ X,
    const ushort_t* __restrict__ Wh, const ushort_t* __restrict__ Wl,
    ushort_t* __restrict__ Ch, ushort_t* __restrict__ Cl,
    int lda, int ldb, int ldc, int K)
{
    __shared__ ushort_t sAh[4096], sAl[4096], sBh[4096], sBl[4096];
    int t = threadIdx.x, lane = t & 63, w = t >> 6;
    int m0 = blockIdx.y << 7, n0 = blockIdx.x << 7;

    f32x4 acc[4][4];
#pragma unroll
    for (int m = 0; m < 4; m++)
#pragma unroll
        for (int n = 0; n < 4; n++) acc[m][n] = (f32x4){0.f, 0.f, 0.f, 0.f};

    int rb = (w >> 1) << 6, cb = (w & 1) << 6, fr = lane & 15, ko = (lane >> 4) << 3;
    int sr = t >> 1, scol = (t & 1) << 4;   // staging: each thread converts 16 A elems

    for (int k0 = 0; k0 < K; k0 += 32) {
        // A tile: fp32 -> hi/lo bf16 in registers -> LDS
        const float* g = X + (size_t)(m0 + sr) * lda + k0 + scol;
        ushort8 H[2], L[2];
#pragma unroll
        for (int qq = 0; qq < 4; qq++) {
            floatx4 v = *(const floatx4*)(g + qq * 4);
#pragma unroll
            for (int j = 0; j < 4; j++) {
                int q = qq * 4 + j;
                ushort_t hh = f2bf(v[j]);
                H[q >> 3][q & 7] = hh;
                L[q >> 3][q & 7] = f2bf(v[j] - bf2f(hh));
            }
        }
        *(ushort8*)&sAh[sr * 32 + scol]     = H[0];
        *(ushort8*)&sAh[sr * 32 + scol + 8] = H[1];
        *(ushort8*)&sAl[sr * 32 + scol]     = L[0];
        *(ushort8*)&sAl[sr * 32 + scol + 8] = L[1];
        // B tiles (pre-split W) via global_load_lds
#pragma unroll
        for (int i = 0; i < 2; i++) {
            int e = ((w << 1) + i) << 9;
            int el = e + lane * 8;
            int r = el >> 5, c = el & 31;
            gll16(Wh + (size_t)(n0 + r) * ldb + k0 + c, sBh + e);
            gll16(Wl + (size_t)(n0 + r) * ldb + k0 + c, sBl + e);
        }
        __syncthreads();

        short8 ah[4], al[4], bh[4], bl[4];
#pragma unroll
        for (int f = 0; f < 4; f++) {
            ah[f] = *(const short8*)&sAh[(rb + f * 16 + fr) * 32 + ko];
            al[f] = *(const short8*)&sAl[(rb + f * 16 + fr) * 32 + ko];
            bh[f] = *(const short8*)&sBh[(cb + f * 16 + fr) * 32 + ko];
            bl[f] = *(const short8*)&sBl[(cb + f * 16 + fr) * 32 + ko];
        }
#pragma unroll
        for (int m = 0; m < 4; m++)
#pragma unroll
            for (int n = 0; n < 4; n++) {
                acc[m][n] = __builtin_amdgcn_mfma_f32_16x16x32_bf16(ah[m], bh[n], acc[m][n], 0, 0, 0);
                acc[m][n] = __builtin_amdgcn_mfma_f32_16x16x32_bf16(ah[m], bl[n], acc[m][n], 0, 0, 0);
                acc[m][n] = __builtin_amdgcn_mfma_f32_16x16x32_bf16(al[m], bh[n], acc[m][n], 0, 0, 0);
            }
        __syncthreads();
    }

    int r0 = rb + ((lane >> 4) << 2);
    int c0 = cb + fr;
#pragma unroll
    for (int m = 0; m < 4; m++)
#pragma unroll
        for (int n = 0; n < 4; n++)
#pragma unroll
            for (int j = 0; j < 4; j++) {
                float vv = acc[m][n][j];
                size_t idx = (size_t)(m0 + r0 + m * 16 + j) * ldc + (n0 + c0 + n * 16);
                ushort_t hh = f2bf(vv);
                Ch[idx] = hh;
                Cl[idx] = f2bf(vv - bf2f(hh));
            }
}

// ---------------- generic bf16 GEMM (both operands K-contiguous), batched ----------------
// NPASS=3: split emulation (Ah,Al,Bh,Bl). NPASS=1: plain bf16 (Ah,Bh only).
template <int NPASS>
__global__ __launch_bounds__(256, 2) void gemm_bf(
    const ushort_t* __restrict__ Ah, const ushort_t* __restrict__ Al,
    const ushort_t* __restrict__ Bh, const ushort_t* __restrict__ Bl,
    float* __restrict__ C,
    int lda, int ldb, int ldc, int K,
    long long bA, long long bB, long long bC)
{
    __shared__ ushort_t sAh[4096], sBh[4096];
    __shared__ ushort_t sAl[NPASS == 3 ? 4096 : 8], sBl[NPASS == 3 ? 4096 : 8];
    int t = threadIdx.x, lane = t & 63, w = t >> 6;
    int m0 = blockIdx.y << 7, n0 = blockIdx.x << 7;
    size_t zA = (size_t)bA * blockIdx.z;
    size_t zB = (size_t)bB * blockIdx.z;
    size_t zC = (size_t)bC * blockIdx.z;
    const ushort_t* pAh = Ah + zA + (size_t)m0 * lda;
    const ushort_t* pBh = Bh + zB + (size_t)n0 * ldb;
    const ushort_t* pAl = (NPASS == 3) ? (Al + zA + (size_t)m0 * lda) : pAh;
    const ushort_t* pBl = (NPASS == 3) ? (Bl + zB + (size_t)n0 * ldb) : pBh;

    f32x4 acc[4][4];
#pragma unroll
    for (int m = 0; m < 4; m++)
#pragma unroll
        for (int n = 0; n < 4; n++) acc[m][n] = (f32x4){0.f, 0.f, 0.f, 0.f};

    int rb = (w >> 1) << 6, cb = (w & 1) << 6, fr = lane & 15, ko = (lane >> 4) << 3;

    for (int k0 = 0; k0 < K; k0 += 32) {
#pragma unroll
        for (int i = 0; i < 2; i++) {
            int e = ((w << 1) + i) << 9;
            int el = e + lane * 8;
            int r = el >> 5, c = el & 31;
            gll16(pAh + (size_t)r * lda + k0 + c, sAh + e);
            gll16(pBh + (size_t)r * ldb + k0 + c, sBh + e);
            if constexpr (NPASS == 3) {
                gll16(pAl + (size_t)r * lda + k0 + c, sAl + e);
                gll16(pBl + (size_t)r * ldb + k0 + c, sBl + e);
            }
        }
        __syncthreads();

        short8 ah[4], bh[4], al[4], bl[4];
#pragma unroll
        for (int f = 0; f < 4; f++) {
            ah[f] = *(const short8*)&sAh[(rb + f * 16 + fr) * 32 + ko];
            bh[f] = *(const short8*)&sBh[(cb + f * 16 + fr) * 32 + ko];
            if constexpr (NPASS == 3) {
                al[f] = *(const short8*)&sAl[(rb + f * 16 + fr) * 32 + ko];
                bl[f] = *(const short8*)&sBl[(cb + f * 16 + fr) * 32 + ko];
            }
        }
#pragma unroll
        for (int m = 0; m < 4; m++)
#pragma unroll
            for (int n = 0; n < 4; n++) {
                acc[m][n] = __builtin_amdgcn_mfma_f32_16x16x32_bf16(ah[m], bh[n], acc[m][n], 0, 0, 0);
                if constexpr (NPASS == 3) {
                    acc[m][n] = __builtin_amdgcn_mfma_f32_16x16x32_bf16(ah[m], bl[n], acc[m][n], 0, 0, 0);
                    acc[m][n] = __builtin_amdgcn_mfma_f32_16x16x32_bf16(al[m], bh[n], acc[m][n], 0, 0, 0);
                }
            }
        __syncthreads();
    }

    int r0 = rb + ((lane >> 4) << 2);
    int c0 = cb + fr;
#pragma unroll
    for (int m = 0; m < 4; m++)
#pragma unroll
        for (int n = 0; n < 4; n++)
#pragma unroll
            for (int j = 0; j < 4; j++)
                C[zC + (size_t)(m0 + r0 + m * 16 + j) * ldc + (n0 + c0 + n * 16)] = acc[m][n][j];
}

// ---------------- row softmax: weights[b][t][s] = softmax_s(scores[b][t][s]) ----------------
__global__ __launch_bounds__(256) void softmax_k(
    const float* __restrict__ sc, ushort_t* __restrict__ wt)
{
    size_t row = blockIdx.x;
    const floatx4* p = (const floatx4*)(sc + row * 1024);
    int t = threadIdx.x, lane = t & 63, w = t >> 6;
    floatx4 v = p[t];
    float m = fmaxf(fmaxf(v[0], v[1]), fmaxf(v[2], v[3]));
#pragma unroll
    for (int o = 1; o < 64; o <<= 1) m = fmaxf(m, __shfl_xor(m, o));
    __shared__ float red[8];
    if (lane == 0) red[w] = m;
    __syncthreads();
    m = fmaxf(fmaxf(red[0], red[1]), fmaxf(red[2], red[3]));
    floatx4 e;
#pragma unroll
    for (int j = 0; j < 4; j++) e[j] = __expf(v[j] - m);
    float s = e[0] + e[1] + e[2] + e[3];
#pragma unroll
    for (int o = 1; o < 64; o <<= 1) s += __shfl_xor(s, o);
    if (lane == 0) red[4 + w] = s;
    __syncthreads();
    s = red[4] + red[5] + red[6] + red[7];
    float inv = 1.0f / s;
    ushort4v o4;
#pragma unroll
    for (int j = 0; j < 4; j++) o4[j] = f2bf(e[j] * inv);
    ((ushort4v*)(wt + row * 1024))[t] = o4;
}

extern "C" void kernel_launch(void* const* d_in, const int* in_sizes, int n_in,
                              void* d_out, int out_size, void* d_ws, size_t ws_size,
                              hipStream_t stream)
{
    const float* src = (const float*)d_in[0];   // (S=1024, B=32, 1024)
    const float* tgt = (const float*)d_in[1];   // (T=1024, B=32, 1024)
    const float* W1  = (const float*)d_in[2];   // (A=1024, 1024)
    const float* W2  = (const float*)d_in[3];
    float* out = (float*)d_out;                 // (T, B, 1024)

    char* ws = (char*)d_ws;
    const size_t MB = 1024ull * 1024ull;
    ushort_t* tsH   = (ushort_t*)(ws);             // 64MB  (S,B,A) hi
    ushort_t* tsL   = (ushort_t*)(ws + 64  * MB);  // 64MB  lo
    ushort_t* ttH   = (ushort_t*)(ws + 128 * MB);  // 64MB  (T,B,A) hi
    ushort_t* ttL   = (ushort_t*)(ws + 192 * MB);  // 64MB  lo
    ushort_t* srcT  = (ushort_t*)(ws + 256 * MB);  // 64MB  (B,D,S) bf16
    float*    scores= (float*)   (ws + 320 * MB);  // 128MB (B,T,S) fp32
    ushort_t* w1H   = (ushort_t*)(ws + 448 * MB);  // 2MB each
    ushort_t* w1L   = (ushort_t*)(ws + 450 * MB);
    ushort_t* w2H   = (ushort_t*)(ws + 452 * MB);
    ushort_t* w2L   = (ushort_t*)(ws + 454 * MB);
    ushort_t* wts   = tsH;                         // weights reuse tsH region (dead by then)

    // prep
    split_f32<<<1024, 256, 0, stream>>>(W1, w1H, w1L, 262144);
    split_f32<<<1024, 256, 0, stream>>>(W2, w2H, w2L, 262144);
    transpose_src_k<<<dim3(32, 32, 32), 256, 0, stream>>>(src, srcT);

    // projections: ts = src*W1^T, tt = tgt*W2^T  (M=32768, N=1024, K=1024)
    gemm_proj<<<dim3(8, 256, 1), 256, 0, stream>>>(src, w1H, w1L, tsH, tsL, 1024, 1024, 1024, 1024);
    gemm_proj<<<dim3(8, 256, 1), 256, 0, stream>>>(tgt, w2H, w2L, ttH, ttL, 1024, 1024, 1024, 1024);

    // scores[b][t][s] = sum_a tt[t,b,a]*ts[s,b,a]   (batched over b)
    gemm_bf<3><<<dim3(8, 8, 32), 256, 0, stream>>>(
        ttH, ttL, tsH, tsL, scores,
        32768, 32768, 1024, 1024,
        1024ll, 1024ll, 1024ll * 1024ll);

    // softmax over s
    softmax_k<<<32768, 256, 0, stream>>>(scores, wts);

    // out[t][b][d] = sum_s wts[b][t][s] * srcT[b][d][s]
    gemm_bf<1><<<dim3(8, 8, 32), 256, 0, stream>>>(
        wts, nullptr, srcT, nullptr, out,
        1024, 1024, 32768, 1024,
        1024ll * 1024ll, 1024ll * 1024ll, 1024ll);
}

// Round 2
// 782.276 us; speedup vs baseline: 1.5503x; 1.5503x over previous
//
#include <hip/hip_runtime.h>
#include <hip/hip_bf16.h>

typedef unsigned short ushort_t;
typedef _Float16 half_t;
typedef __attribute__((ext_vector_type(8))) _Float16 half8;
typedef __attribute__((ext_vector_type(4))) _Float16 half4;
typedef __attribute__((ext_vector_type(4))) float floatx4;
typedef __attribute__((ext_vector_type(4))) float f32x4;

#define DEVFN static __device__ __forceinline__

// async global->LDS, 16B per lane; lds dest must be wave-uniform base
DEVFN void gll16(const void* g, void* l) {
    __builtin_amdgcn_global_load_lds(
        (const __attribute__((address_space(1))) unsigned int*)g,
        (__attribute__((address_space(3))) unsigned int*)l, 16, 0, 0);
}

// ---------------- prep: fp32 -> fp16 ----------------
__global__ __launch_bounds__(256) void cvt_f16(
    const float* __restrict__ in, half_t* __restrict__ out, int n4)
{
    int i = blockIdx.x * 256 + threadIdx.x;
    if (i >= n4) return;
    floatx4 v = ((const floatx4*)in)[i];
    half4 h;
#pragma unroll
    for (int j = 0; j < 4; j++) h[j] = (half_t)v[j];
    ((half4*)out)[i] = h;
}

// ---------------- prep: srcT[b][d][s] = fp16(source[s][b][d]) ----------------
__global__ __launch_bounds__(256) void transpose_src_f16(
    const float* __restrict__ src, half_t* __restrict__ srcT)
{
    __shared__ float tile[32][33];
    int s0 = blockIdx.x << 5, d0 = blockIdx.y << 5, b = blockIdx.z;
    int t = threadIdx.x;
    int si = t >> 3, dj = (t & 7) << 2;
    floatx4 v = *(const floatx4*)&src[((size_t)(s0 + si) * 32 + b) * 1024 + d0 + dj];
    tile[si][dj + 0] = v[0]; tile[si][dj + 1] = v[1];
    tile[si][dj + 2] = v[2]; tile[si][dj + 3] = v[3];
    __syncthreads();
    int di = t >> 3, sj = (t & 7) << 2;
    half4 o;
#pragma unroll
    for (int q = 0; q < 4; q++) o[q] = (half_t)tile[sj + q][di];
    *(half4*)&srcT[((size_t)b * 1024 + d0 + di) * 1024 + s0 + sj] = o;
}

// ---------------- fp16 GEMM, both operands K-contiguous, batched ----------------
// C(MxN) = A(MxK) * B(NxK)^T ; 128x128 tile, BK=32, 4 waves (m97 structure).
// 1-D grid with bijective XCD swizzle (nwg % 8 == 0); logical dims (gx, gy, gz).
template <bool OUT_F16>
__global__ __launch_bounds__(256, 2) void gemm_f16(
    const half_t* __restrict__ A, const half_t* __restrict__ B,
    void* __restrict__ Cv,
    int lda, int ldb, int ldc, int K,
    long long bA, long long bB, long long bC,
    int gx, int gy)
{
    __shared__ half_t sA[4096], sB[4096];
    int nwg = gridDim.x;
    int bid = blockIdx.x;
    int sw = (bid & 7) * (nwg >> 3) + (bid >> 3);   // XCD k gets contiguous chunk
    int x = sw % gx;
    int r1 = sw / gx;
    int y = r1 % gy;
    int z = r1 / gy;

    int t = threadIdx.x, lane = t & 63, w = t >> 6;
    int m0 = y << 7, n0 = x << 7;
    size_t zA = (size_t)bA * z, zB = (size_t)bB * z, zC = (size_t)bC * z;
    const half_t* pA = A + zA + (size_t)m0 * lda;
    const half_t* pB = B + zB + (size_t)n0 * ldb;

    f32x4 acc[4][4];
#pragma unroll
    for (int m = 0; m < 4; m++)
#pragma unroll
        for (int n = 0; n < 4; n++) acc[m][n] = (f32x4){0.f, 0.f, 0.f, 0.f};

    int rb = (w >> 1) << 6, cb = (w & 1) << 6, fr = lane & 15, ko = (lane >> 4) << 3;

    for (int k0 = 0; k0 < K; k0 += 32) {
#pragma unroll
        for (int i = 0; i < 2; i++) {
            int e = ((w << 1) + i) << 9;      // half_t offset of this wave's 1KB chunk
            int el = e + lane * 8;
            int r = el >> 5, c = el & 31;
            gll16(pA + (size_t)r * lda + k0 + c, sA + e);
            gll16(pB + (size_t)r * ldb + k0 + c, sB + e);
        }
        __syncthreads();

        half8 ah[4], bh[4];
#pragma unroll
        for (int f = 0; f < 4; f++) {
            ah[f] = *(const half8*)&sA[(rb + f * 16 + fr) * 32 + ko];
            bh[f] = *(const half8*)&sB[(cb + f * 16 + fr) * 32 + ko];
        }
#pragma unroll
        for (int m = 0; m < 4; m++)
#pragma unroll
            for (int n = 0; n < 4; n++)
                acc[m][n] = __builtin_amdgcn_mfma_f32_16x16x32_f16(ah[m], bh[n], acc[m][n], 0, 0, 0);
        __syncthreads();
    }

    int r0 = rb + ((lane >> 4) << 2);
    int c0 = cb + fr;
#pragma unroll
    for (int m = 0; m < 4; m++)
#pragma unroll
        for (int n = 0; n < 4; n++)
#pragma unroll
            for (int j = 0; j < 4; j++) {
                size_t idx = zC + (size_t)(m0 + r0 + m * 16 + j) * ldc + (n0 + c0 + n * 16);
                if constexpr (OUT_F16)
                    ((half_t*)Cv)[idx] = (half_t)acc[m][n][j];
                else
                    ((float*)Cv)[idx] = acc[m][n][j];
            }
}

// ---------------- row softmax: weights[b][t][s] = softmax_s(scores[b][t][s]) ----------------
__global__ __launch_bounds__(256) void softmax_k(
    const float* __restrict__ sc, half_t* __restrict__ wt)
{
    size_t row = blockIdx.x;
    const floatx4* p = (const floatx4*)(sc + row * 1024);
    int t = threadIdx.x, lane = t & 63, w = t >> 6;
    floatx4 v = p[t];
    float m = fmaxf(fmaxf(v[0], v[1]), fmaxf(v[2], v[3]));
#pragma unroll
    for (int o = 1; o < 64; o <<= 1) m = fmaxf(m, __shfl_xor(m, o));
    __shared__ float red[8];
    if (lane == 0) red[w] = m;
    __syncthreads();
    m = fmaxf(fmaxf(red[0], red[1]), fmaxf(red[2], red[3]));
    floatx4 e;
#pragma unroll
    for (int j = 0; j < 4; j++) e[j] = __expf(v[j] - m);
    float s = e[0] + e[1] + e[2] + e[3];
#pragma unroll
    for (int o = 1; o < 64; o <<= 1) s += __shfl_xor(s, o);
    if (lane == 0) red[4 + w] = s;
    __syncthreads();
    s = red[4] + red[5] + red[6] + red[7];
    float inv = 1.0f / s;
    half4 o4;
#pragma unroll
    for (int j = 0; j < 4; j++) o4[j] = (half_t)(e[j] * inv);
    ((half4*)(wt + row * 1024))[t] = o4;
}

extern "C" void kernel_launch(void* const* d_in, const int* in_sizes, int n_in,
                              void* d_out, int out_size, void* d_ws, size_t ws_size,
                              hipStream_t stream)
{
    const float* src = (const float*)d_in[0];   // (S=1024, B=32, 1024)
    const float* tgt = (const float*)d_in[1];   // (T=1024, B=32, 1024)
    const float* W1  = (const float*)d_in[2];   // (A=1024, 1024)
    const float* W2  = (const float*)d_in[3];
    float* out = (float*)d_out;                 // (T, B, 1024)

    char* ws = (char*)d_ws;
    const size_t MB = 1024ull * 1024ull;
    half_t* srcH  = (half_t*)(ws);              // 64MB (S,B,D) fp16
    half_t* tgtH  = (half_t*)(ws + 64  * MB);   // 64MB (T,B,D) fp16
    half_t* tsH   = (half_t*)(ws + 128 * MB);   // 64MB (S,B,A) fp16
    half_t* ttH   = (half_t*)(ws + 192 * MB);   // 64MB (T,B,A) fp16
    half_t* srcT  = (half_t*)(ws + 256 * MB);   // 64MB (B,D,S) fp16
    float*  scores= (float*) (ws + 320 * MB);   // 128MB (B,T,S) fp32
    half_t* w1h   = (half_t*)(ws + 448 * MB);   // 2MB
    half_t* w2h   = (half_t*)(ws + 450 * MB);   // 2MB
    half_t* wts   = srcH;                       // weights reuse srcH (dead after projections)

    // prep: fp32 -> fp16
    cvt_f16<<<32768, 256, 0, stream>>>(src, srcH, 8388608);
    cvt_f16<<<32768, 256, 0, stream>>>(tgt, tgtH, 8388608);
    cvt_f16<<<1024, 256, 0, stream>>>(W1, w1h, 262144);
    cvt_f16<<<1024, 256, 0, stream>>>(W2, w2h, 262144);
    transpose_src_f16<<<dim3(32, 32, 32), 256, 0, stream>>>(src, srcT);

    // projections: ts = src*W1^T, tt = tgt*W2^T  (M=32768, N=1024, K=1024)
    gemm_f16<true><<<2048, 256, 0, stream>>>(srcH, w1h, tsH,
        1024, 1024, 1024, 1024, 0ll, 0ll, 0ll, 8, 256);
    gemm_f16<true><<<2048, 256, 0, stream>>>(tgtH, w2h, ttH,
        1024, 1024, 1024, 1024, 0ll, 0ll, 0ll, 8, 256);

    // scores[b][t][s] = sum_a tt[t,b,a]*ts[s,b,a]  (batched over b)
    gemm_f16<false><<<2048, 256, 0, stream>>>(ttH, tsH, scores,
        32768, 32768, 1024, 1024, 1024ll, 1024ll, 1024ll * 1024ll, 8, 8);

    // softmax over s
    softmax_k<<<32768, 256, 0, stream>>>(scores, wts);

    // out[t][b][d] = sum_s wts[b][t][s] * srcT[b][d][s]
    gemm_f16<false><<<2048, 256, 0, stream>>>(wts, srcT, out,
        1024, 1024, 32768, 1024, 1024ll * 1024ll, 1024ll * 1024ll, 1024ll, 8, 8);
}

// Round 3
// 707.671 us; speedup vs baseline: 1.7137x; 1.1054x over previous
//
#include <hip/hip_runtime.h>
#include <hip/hip_bf16.h>

typedef _Float16 half_t;
typedef __attribute__((ext_vector_type(8))) _Float16 half8;
typedef __attribute__((ext_vector_type(4))) _Float16 half4;
typedef __attribute__((ext_vector_type(4))) float floatx4;
typedef __attribute__((ext_vector_type(4))) float f32x4;

#define DEVFN static __device__ __forceinline__

// async global->LDS, 16B per lane; lds dest must be wave-uniform base
DEVFN void gll16(const void* g, void* l) {
    __builtin_amdgcn_global_load_lds(
        (const __attribute__((address_space(1))) unsigned int*)g,
        (__attribute__((address_space(3))) unsigned int*)l, 16, 0, 0);
}
DEVFN f32x4 mfma16(half8 a, half8 b, f32x4 c) {
    return __builtin_amdgcn_mfma_f32_16x16x32_f16(a, b, c, 0, 0, 0);
}
DEVFN void lgkm0() { asm volatile("s_waitcnt lgkmcnt(0)" ::: "memory"); __builtin_amdgcn_sched_barrier(0); }
DEVFN void vm0()   { asm volatile("s_waitcnt vmcnt(0)"   ::: "memory"); __builtin_amdgcn_sched_barrier(0); }
DEVFN void vm2()   { asm volatile("s_waitcnt vmcnt(2)"   ::: "memory"); __builtin_amdgcn_sched_barrier(0); }
DEVFN void vm4()   { asm volatile("s_waitcnt vmcnt(4)"   ::: "memory"); __builtin_amdgcn_sched_barrier(0); }
DEVFN void bar()   { __builtin_amdgcn_s_barrier(); __builtin_amdgcn_sched_barrier(0); }

// ---------------- prep: fp32 -> fp16 ----------------
__global__ __launch_bounds__(256) void cvt_f16(
    const float* __restrict__ in, half_t* __restrict__ out, int n4)
{
    int i = blockIdx.x * 256 + threadIdx.x;
    if (i >= n4) return;
    floatx4 v = ((const floatx4*)in)[i];
    half4 h;
#pragma unroll
    for (int j = 0; j < 4; j++) h[j] = (half_t)v[j];
    ((half4*)out)[i] = h;
}

// ---------------- prep: srcT[b][d][s] + srcH[s][b][d] = fp16(source) ----------------
__global__ __launch_bounds__(256) void transpose_src_f16(
    const float* __restrict__ src, half_t* __restrict__ srcT, half_t* __restrict__ srcH)
{
    __shared__ float tile[32][33];
    int s0 = blockIdx.x << 5, d0 = blockIdx.y << 5, b = blockIdx.z;
    int t = threadIdx.x;
    int si = t >> 3, dj = (t & 7) << 2;
    floatx4 v = *(const floatx4*)&src[((size_t)(s0 + si) * 32 + b) * 1024 + d0 + dj];
    tile[si][dj + 0] = v[0]; tile[si][dj + 1] = v[1];
    tile[si][dj + 2] = v[2]; tile[si][dj + 3] = v[3];
    half4 hv;
#pragma unroll
    for (int j = 0; j < 4; j++) hv[j] = (half_t)v[j];
    *(half4*)&srcH[((size_t)(s0 + si) * 32 + b) * 1024 + d0 + dj] = hv;
    __syncthreads();
    int di = t >> 3, sj = (t & 7) << 2;
    half4 o;
#pragma unroll
    for (int q = 0; q < 4; q++) o[q] = (half_t)tile[sj + q][di];
    *(half4*)&srcT[((size_t)b * 1024 + d0 + di) * 1024 + s0 + sj] = o;
}

// ---------------- fp16 GEMM: 256x256 tile, BK=64 (2 K-halves), 8 waves, ----------------
// double-buffered LDS (128KB), 4 phases/K-tile, counted vmcnt (never 0 in main loop).
// C(MxN) = A(MxK) * B(NxK)^T, batched; 1-D grid w/ bijective XCD swizzle (nwg%8==0).
template <bool OUT_F16>
__global__ __launch_bounds__(512, 2) void gemm256(
    const half_t* __restrict__ A, const half_t* __restrict__ B,
    void* __restrict__ Cv,
    int lda, int ldb, int ldc, int K,
    long long bA, long long bB, long long bC,
    int gx, int gy)
{
    __shared__ char lds[131072];
    // layout: A: buf*32768 + kh*16384        (256 rows x 32 halfs = 64B rows)
    //         B: 65536 + buf*32768 + kh*16384
    const int nwg = gridDim.x;
    const int bid = blockIdx.x;
    const int sw = (bid & 7) * (nwg >> 3) + (bid >> 3);
    const int x = sw % gx;
    const int r1 = sw / gx;
    const int y = r1 % gy;
    const int z = r1 / gy;

    const int t = threadIdx.x, lane = t & 63, w = t >> 6;
    const int wr = w >> 2, wc = w & 3;              // wave covers rows wr*128..+128, cols wc*64..+64
    const int m0 = y << 8, n0 = x << 8;
    const half_t* pA = A + (size_t)bA * z + (size_t)m0 * lda;
    const half_t* pB = B + (size_t)bB * z + (size_t)n0 * ldb;

    // staging: per K-half (256 rows x 32 halfs = 16KB), 1024 slots of 16B, 2 per thread
    int srow[2], scol[2];
#pragma unroll
    for (int i = 0; i < 2; i++) {
        int slot = (w << 7) + (i << 6) + lane;
        srow[i] = slot >> 2;                        // 0..255
        scol[i] = (slot & 3) << 3;                  // 0,8,16,24 halfs
    }
    const unsigned stOff = (unsigned)((w << 7) << 4);   // wave-uniform LDS byte base (+i*1024)

    const int lr = lane & 15, q = lane >> 4;
    const unsigned aRd = (unsigned)((((wr << 7) + lr) << 6) + (q << 4));           // + m*1024
    const unsigned bRd = 65536u + (unsigned)((((wc << 6) + lr) << 6) + (q << 4));  // + fn*1024

    f32x4 acc[8][4];
#pragma unroll
    for (int m = 0; m < 8; m++)
#pragma unroll
        for (int n = 0; n < 4; n++) acc[m][n] = (f32x4){0.f, 0.f, 0.f, 0.f};

    auto stA = [&](int nb, int kh, int kc) {
#pragma unroll
        for (int i = 0; i < 2; i++)
            gll16(pA + (size_t)srow[i] * lda + (kc + kh * 32 + scol[i]),
                  lds + (nb << 15) + (kh << 14) + stOff + (i << 10));
    };
    auto stB = [&](int nb, int kh, int kc) {
#pragma unroll
        for (int i = 0; i < 2; i++)
            gll16(pB + (size_t)srow[i] * ldb + (kc + kh * 32 + scol[i]),
                  lds + 65536 + (nb << 15) + (kh << 14) + stOff + (i << 10));
    };

    // prologue: stage K-tile 0 into buf0; wait A-kh0/A-kh1/B-kh0 (leave B-kh1 in flight)
    stA(0, 0, 0); stA(0, 1, 0); stB(0, 0, 0); stB(0, 1, 0);
    vm2();
    bar();

    half8 av[8], bv[2], bv2[2];
    const int NT = K >> 6;
    for (int tt = 0; tt < NT; ++tt) {
        const int buf = tt & 1, nb = buf ^ 1;
        const bool st = (tt + 1 < NT);
        const int kn = (tt + 1) << 6;
        const unsigned base0 = (unsigned)(buf << 15);
        const unsigned base1 = base0 + 16384u;

        // ---- P1: kk=0, n-quad 0 ----
#pragma unroll
        for (int m = 0; m < 8; m++) av[m] = *(const half8*)(lds + base0 + aRd + m * 1024);
#pragma unroll
        for (int n = 0; n < 2; n++) bv[n] = *(const half8*)(lds + base0 + bRd + n * 1024);
        if (st) stA(nb, 0, kn);
        bar();
        lgkm0();
        __builtin_amdgcn_s_setprio(1);
#pragma unroll
        for (int m = 0; m < 8; m++) {
            acc[m][0] = mfma16(av[m], bv[0], acc[m][0]);
            acc[m][1] = mfma16(av[m], bv[1], acc[m][1]);
        }
        __builtin_amdgcn_s_setprio(0);
        bar();

        // ---- P2: kk=0, n-quad 1 ----
#pragma unroll
        for (int n = 0; n < 2; n++) bv2[n] = *(const half8*)(lds + base0 + bRd + (2 + n) * 1024);
        if (st) stA(nb, 1, kn);
        bar();
        lgkm0();
        __builtin_amdgcn_s_setprio(1);
#pragma unroll
        for (int m = 0; m < 8; m++) {
            acc[m][2] = mfma16(av[m], bv2[0], acc[m][2]);
            acc[m][3] = mfma16(av[m], bv2[1], acc[m][3]);
        }
        __builtin_amdgcn_s_setprio(0);
        if (st) vm4(); else vm0();     // B-kh1(cur) landed before P3 reads it
        bar();

        // ---- P3: kk=1, n-quad 0 ----
#pragma unroll
        for (int m = 0; m < 8; m++) av[m] = *(const half8*)(lds + base1 + aRd + m * 1024);
#pragma unroll
        for (int n = 0; n < 2; n++) bv[n] = *(const half8*)(lds + base1 + bRd + n * 1024);
        if (st) stB(nb, 0, kn);
        bar();
        lgkm0();
        __builtin_amdgcn_s_setprio(1);
#pragma unroll
        for (int m = 0; m < 8; m++) {
            acc[m][0] = mfma16(av[m], bv[0], acc[m][0]);
            acc[m][1] = mfma16(av[m], bv[1], acc[m][1]);
        }
        __builtin_amdgcn_s_setprio(0);
        bar();

        // ---- P4: kk=1, n-quad 1 ----
#pragma unroll
        for (int n = 0; n < 2; n++) bv2[n] = *(const half8*)(lds + base1 + bRd + (2 + n) * 1024);
        if (st) stB(nb, 1, kn);
        bar();
        lgkm0();
        __builtin_amdgcn_s_setprio(1);
#pragma unroll
        for (int m = 0; m < 8; m++) {
            acc[m][2] = mfma16(av[m], bv2[0], acc[m][2]);
            acc[m][3] = mfma16(av[m], bv2[1], acc[m][3]);
        }
        __builtin_amdgcn_s_setprio(0);
        if (st) vm2();                 // A-kh0/A-kh1/B-kh0(next) landed before next P1
        bar();
    }

    // ---- epilogue ----
    const size_t zC = (size_t)bC * z;
    const int r0 = m0 + (wr << 7) + (q << 2);
    const int c0 = n0 + (wc << 6) + lr;
#pragma unroll
    for (int m = 0; m < 8; m++)
#pragma unroll
        for (int fn = 0; fn < 4; fn++)
#pragma unroll
            for (int j = 0; j < 4; j++) {
                size_t idx = zC + (size_t)(r0 + m * 16 + j) * ldc + (c0 + fn * 16);
                if constexpr (OUT_F16)
                    ((half_t*)Cv)[idx] = (half_t)acc[m][fn][j];
                else
                    ((float*)Cv)[idx] = acc[m][fn][j];
            }
}

// ---------------- row softmax: weights[b][t][s] = softmax_s(scores[b][t][s]) ----------------
__global__ __launch_bounds__(256) void softmax_k(
    const float* __restrict__ sc, half_t* __restrict__ wt)
{
    size_t row = blockIdx.x;
    const floatx4* p = (const floatx4*)(sc + row * 1024);
    int t = threadIdx.x, lane = t & 63, w = t >> 6;
    floatx4 v = p[t];
    float m = fmaxf(fmaxf(v[0], v[1]), fmaxf(v[2], v[3]));
#pragma unroll
    for (int o = 1; o < 64; o <<= 1) m = fmaxf(m, __shfl_xor(m, o));
    __shared__ float red[8];
    if (lane == 0) red[w] = m;
    __syncthreads();
    m = fmaxf(fmaxf(red[0], red[1]), fmaxf(red[2], red[3]));
    floatx4 e;
#pragma unroll
    for (int j = 0; j < 4; j++) e[j] = __expf(v[j] - m);
    float s = e[0] + e[1] + e[2] + e[3];
#pragma unroll
    for (int o = 1; o < 64; o <<= 1) s += __shfl_xor(s, o);
    if (lane == 0) red[4 + w] = s;
    __syncthreads();
    s = red[4] + red[5] + red[6] + red[7];
    float inv = 1.0f / s;
    half4 o4;
#pragma unroll
    for (int j = 0; j < 4; j++) o4[j] = (half_t)(e[j] * inv);
    ((half4*)(wt + row * 1024))[t] = o4;
}

extern "C" void kernel_launch(void* const* d_in, const int* in_sizes, int n_in,
                              void* d_out, int out_size, void* d_ws, size_t ws_size,
                              hipStream_t stream)
{
    const float* src = (const float*)d_in[0];   // (S=1024, B=32, 1024)
    const float* tgt = (const float*)d_in[1];   // (T=1024, B=32, 1024)
    const float* W1  = (const float*)d_in[2];   // (A=1024, 1024)
    const float* W2  = (const float*)d_in[3];
    float* out = (float*)d_out;                 // (T, B, 1024)

    char* ws = (char*)d_ws;
    const size_t MB = 1024ull * 1024ull;
    half_t* srcH  = (half_t*)(ws);              // 64MB (S,B,D) fp16
    half_t* tgtH  = (half_t*)(ws + 64  * MB);   // 64MB (T,B,D) fp16
    half_t* tsH   = (half_t*)(ws + 128 * MB);   // 64MB (S,B,A) fp16
    half_t* ttH   = (half_t*)(ws + 192 * MB);   // 64MB (T,B,A) fp16
    half_t* srcT  = (half_t*)(ws + 256 * MB);   // 64MB (B,D,S) fp16
    float*  scores= (float*) (ws + 320 * MB);   // 128MB (B,T,S) fp32
    half_t* w1h   = (half_t*)(ws + 448 * MB);   // 2MB
    half_t* w2h   = (half_t*)(ws + 450 * MB);   // 2MB
    half_t* wts   = srcH;                       // weights reuse srcH (dead after proj1)

    // prep: fp32 -> fp16 (+ transposed source)
    cvt_f16<<<32768, 256, 0, stream>>>(tgt, tgtH, 8388608);
    cvt_f16<<<1024, 256, 0, stream>>>(W1, w1h, 262144);
    cvt_f16<<<1024, 256, 0, stream>>>(W2, w2h, 262144);
    transpose_src_f16<<<dim3(32, 32, 32), 256, 0, stream>>>(src, srcT, srcH);

    // projections: ts = src*W1^T, tt = tgt*W2^T  (M=32768, N=1024, K=1024)
    gemm256<true><<<512, 512, 0, stream>>>(srcH, w1h, tsH,
        1024, 1024, 1024, 1024, 0ll, 0ll, 0ll, 4, 128);
    gemm256<true><<<512, 512, 0, stream>>>(tgtH, w2h, ttH,
        1024, 1024, 1024, 1024, 0ll, 0ll, 0ll, 4, 128);

    // scores[b][t][s] = sum_a tt[t,b,a]*ts[s,b,a]  (batched over b)
    gemm256<false><<<512, 512, 0, stream>>>(ttH, tsH, scores,
        32768, 32768, 1024, 1024, 1024ll, 1024ll, 1024ll * 1024ll, 4, 4);

    // softmax over s
    softmax_k<<<32768, 256, 0, stream>>>(scores, wts);

    // out[t][b][d] = sum_s wts[b][t][s] * srcT[b][d][s]
    gemm256<false><<<512, 512, 0, stream>>>(wts, srcT, out,
        1024, 1024, 32768, 1024, 1024ll * 1024ll, 1024ll * 1024ll, 1024ll, 4, 4);
}

// Round 4
// 701.070 us; speedup vs baseline: 1.7298x; 1.0094x over previous
//
#include <hip/hip_runtime.h>
#include <hip/hip_bf16.h>

typedef _Float16 half_t;
typedef __attribute__((ext_vector_type(8))) _Float16 half8;
typedef __attribute__((ext_vector_type(4))) _Float16 half4;
typedef __attribute__((ext_vector_type(4))) float floatx4;
typedef __attribute__((ext_vector_type(4))) float f32x4;

#define DEVFN static __device__ __forceinline__

// async global->LDS, 16B per lane; lds dest must be wave-uniform base
DEVFN void gll16(const void* g, void* l) {
    __builtin_amdgcn_global_load_lds(
        (const __attribute__((address_space(1))) unsigned int*)g,
        (__attribute__((address_space(3))) unsigned int*)l, 16, 0, 0);
}
DEVFN f32x4 mfma16(half8 a, half8 b, f32x4 c) {
    return __builtin_amdgcn_mfma_f32_16x16x32_f16(a, b, c, 0, 0, 0);
}
DEVFN void vm0() { asm volatile("s_waitcnt vmcnt(0)" ::: "memory"); __builtin_amdgcn_sched_barrier(0); }
DEVFN void vm4() { asm volatile("s_waitcnt vmcnt(4)" ::: "memory"); __builtin_amdgcn_sched_barrier(0); }
DEVFN void bar() { __builtin_amdgcn_s_barrier(); __builtin_amdgcn_sched_barrier(0); }

// ---------------- prep: fp32 -> fp16 ----------------
__global__ __launch_bounds__(256) void cvt_f16(
    const float* __restrict__ in, half_t* __restrict__ out, int n4)
{
    int i = blockIdx.x * 256 + threadIdx.x;
    if (i >= n4) return;
    floatx4 v = ((const floatx4*)in)[i];
    half4 h;
#pragma unroll
    for (int j = 0; j < 4; j++) h[j] = (half_t)v[j];
    ((half4*)out)[i] = h;
}

// ---------------- prep: srcT[b][d][s] + srcH[s][b][d] = fp16(source) ----------------
__global__ __launch_bounds__(256) void transpose_src_f16(
    const float* __restrict__ src, half_t* __restrict__ srcT, half_t* __restrict__ srcH)
{
    __shared__ float tile[32][33];
    int s0 = blockIdx.x << 5, d0 = blockIdx.y << 5, b = blockIdx.z;
    int t = threadIdx.x;
    int si = t >> 3, dj = (t & 7) << 2;
    floatx4 v = *(const floatx4*)&src[((size_t)(s0 + si) * 32 + b) * 1024 + d0 + dj];
    tile[si][dj + 0] = v[0]; tile[si][dj + 1] = v[1];
    tile[si][dj + 2] = v[2]; tile[si][dj + 3] = v[3];
    half4 hv;
#pragma unroll
    for (int j = 0; j < 4; j++) hv[j] = (half_t)v[j];
    *(half4*)&srcH[((size_t)(s0 + si) * 32 + b) * 1024 + d0 + dj] = hv;
    __syncthreads();
    int di = t >> 3, sj = (t & 7) << 2;
    half4 o;
#pragma unroll
    for (int q = 0; q < 4; q++) o[q] = (half_t)tile[sj + q][di];
    *(half4*)&srcT[((size_t)b * 1024 + d0 + di) * 1024 + s0 + sj] = o;
}

// ---------------- fp16 GEMM: 256x256 tile, BK=64, 8 waves, dbuf LDS, ----------------
// overlap schedule: 2 barriers + 2 counted vmcnt per K-tile, issue-early ds_reads.
// C(MxN) = A(MxK)*B(NxK)^T, batched; 1-D grid w/ XCD swizzle (nwg%8==0).
template <bool OUT_F16>
__global__ __launch_bounds__(512, 2) void gemm256(
    const half_t* __restrict__ A, const half_t* __restrict__ B,
    void* __restrict__ Cv,
    int lda, int ldb, int ldc, int K,
    long long bA, long long bB, long long bC,
    int gx, int gy)
{
    __shared__ char lds[131072];
    // A: buf*32768 + kh*16384 (256 rows x 32 halfs = 64B rows); B: +65536
    const int nwg = gridDim.x;
    const int bid = blockIdx.x;
    const int sw = (bid & 7) * (nwg >> 3) + (bid >> 3);
    const int x = sw % gx;
    const int r1 = sw / gx;
    const int y = r1 % gy;
    const int z = r1 / gy;

    const int t = threadIdx.x, lane = t & 63, w = t >> 6;
    const int wr = w >> 2, wc = w & 3;           // wave tile: rows wr*128..+128, cols wc*64..+64
    const int m0 = y << 8, n0 = x << 8;
    const half_t* pA = A + (size_t)bA * z + (size_t)m0 * lda;
    const half_t* pB = B + (size_t)bB * z + (size_t)n0 * ldb;

    // staging: per K-half (256 rows x 32 halfs = 16KB), 1024 slots of 16B, 2/thread
    int srow[2], scol[2];
#pragma unroll
    for (int i = 0; i < 2; i++) {
        int slot = (w << 7) + (i << 6) + lane;
        srow[i] = slot >> 2;
        scol[i] = (slot & 3) << 3;
    }
    const unsigned stOff = (unsigned)((w << 7) << 4);   // wave-uniform byte base

    const int lr = lane & 15, q = lane >> 4;
    const unsigned aRd = (unsigned)((((wr << 7) + lr) << 6) + (q << 4));           // + m*1024
    const unsigned bRd = 65536u + (unsigned)((((wc << 6) + lr) << 6) + (q << 4));  // + n*1024

    f32x4 acc[8][4];
#pragma unroll
    for (int m = 0; m < 8; m++)
#pragma unroll
        for (int n = 0; n < 4; n++) acc[m][n] = (f32x4){0.f, 0.f, 0.f, 0.f};

    auto stA = [&](int nb, int kh, int kc) {
#pragma unroll
        for (int i = 0; i < 2; i++)
            gll16(pA + (size_t)srow[i] * lda + (kc + kh * 32 + scol[i]),
                  lds + (nb << 15) + (kh << 14) + stOff + (i << 10));
    };
    auto stB = [&](int nb, int kh, int kc) {
#pragma unroll
        for (int i = 0; i < 2; i++)
            gll16(pB + (size_t)srow[i] * ldb + (kc + kh * 32 + scol[i]),
                  lds + 65536 + (nb << 15) + (kh << 14) + stOff + (i << 10));
    };

    // prologue: stage tile 0 into buf0 in order L1=A-kh0, L2=B-kh0, L3=A-kh1, L4=B-kh1
    stA(0, 0, 0); stB(0, 0, 0); stA(0, 1, 0); stB(0, 1, 0);

    half8 av_a[4], av_b[4], bv0[4], bv1[4];
    const int NT = K >> 6;
    for (int tt = 0; tt < NT; ++tt) {
        const int buf = tt & 1, nb = buf ^ 1;
        const bool st = (tt + 1 < NT);
        const int kn = (tt + 1) << 6;
        const unsigned b0 = (unsigned)(buf << 15);
        const unsigned b1 = b0 + 16384u;

        // ---- B0: publish kh0(t); all reads of nb finished last tile ----
        vm4();                      // drain L1,L2(t); L3,L4(t) stay in flight
        bar();
        if (st) stA(nb, 0, kn);     // L1(t+1)
        // kh0 reads, issue-early: av_a(m0-3), bv0(n0-3), av_b(m4-7)
#pragma unroll
        for (int m = 0; m < 4; m++) av_a[m] = *(const half8*)(lds + b0 + aRd + m * 1024);
#pragma unroll
        for (int n = 0; n < 4; n++) bv0[n] = *(const half8*)(lds + b0 + bRd + n * 1024);
#pragma unroll
        for (int m = 0; m < 4; m++) av_b[m] = *(const half8*)(lds + b0 + aRd + (4 + m) * 1024);
        __builtin_amdgcn_s_setprio(1);
#pragma unroll
        for (int m = 0; m < 4; m++)
#pragma unroll
            for (int n = 0; n < 4; n++)
                acc[m][n] = mfma16(av_a[m], bv0[n], acc[m][n]);   // MFMA_A (av_b still flying)
        __builtin_amdgcn_s_setprio(0);
        if (st) stB(nb, 0, kn);     // L2(t+1)

        // ---- BM: publish kh1(t) ----
        if (st) vm4(); else vm0();  // drain L3,L4(t)
        bar();
        // kh1 reads fly under MFMA_B
#pragma unroll
        for (int m = 0; m < 4; m++) av_a[m] = *(const half8*)(lds + b1 + aRd + m * 1024);
#pragma unroll
        for (int n = 0; n < 4; n++) bv1[n] = *(const half8*)(lds + b1 + bRd + n * 1024);
        __builtin_amdgcn_s_setprio(1);
#pragma unroll
        for (int m = 0; m < 4; m++)
#pragma unroll
            for (int n = 0; n < 4; n++)
                acc[4 + m][n] = mfma16(av_b[m], bv0[n], acc[4 + m][n]);  // MFMA_B
        __builtin_amdgcn_s_setprio(0);
        if (st) stA(nb, 1, kn);     // L3(t+1)
#pragma unroll
        for (int m = 0; m < 4; m++) av_b[m] = *(const half8*)(lds + b1 + aRd + (4 + m) * 1024);
        __builtin_amdgcn_s_setprio(1);
#pragma unroll
        for (int m = 0; m < 4; m++)
#pragma unroll
            for (int n = 0; n < 4; n++)
                acc[m][n] = mfma16(av_a[m], bv1[n], acc[m][n]);          // MFMA_C
        __builtin_amdgcn_s_setprio(0);
        if (st) stB(nb, 1, kn);     // L4(t+1)
        __builtin_amdgcn_s_setprio(1);
#pragma unroll
        for (int m = 0; m < 4; m++)
#pragma unroll
            for (int n = 0; n < 4; n++)
                acc[4 + m][n] = mfma16(av_b[m], bv1[n], acc[4 + m][n]);  // MFMA_D
        __builtin_amdgcn_s_setprio(0);
    }

    // ---- epilogue ----
    const size_t zC = (size_t)bC * z;
    const int r0 = m0 + (wr << 7) + (q << 2);
    const int c0 = n0 + (wc << 6) + lr;
#pragma unroll
    for (int m = 0; m < 8; m++)
#pragma unroll
        for (int fn = 0; fn < 4; fn++)
#pragma unroll
            for (int j = 0; j < 4; j++) {
                size_t idx = zC + (size_t)(r0 + m * 16 + j) * ldc + (c0 + fn * 16);
                if constexpr (OUT_F16)
                    ((half_t*)Cv)[idx] = (half_t)acc[m][fn][j];
                else
                    ((float*)Cv)[idx] = acc[m][fn][j];
            }
}

// ---------------- row softmax: weights[b][t][s] = softmax_s(scores[b][t][s]) ----------------
__global__ __launch_bounds__(256) void softmax_k(
    const float* __restrict__ sc, half_t* __restrict__ wt)
{
    size_t row = blockIdx.x;
    const floatx4* p = (const floatx4*)(sc + row * 1024);
    int t = threadIdx.x, lane = t & 63, w = t >> 6;
    floatx4 v = p[t];
    float m = fmaxf(fmaxf(v[0], v[1]), fmaxf(v[2], v[3]));
#pragma unroll
    for (int o = 1; o < 64; o <<= 1) m = fmaxf(m, __shfl_xor(m, o));
    __shared__ float red[8];
    if (lane == 0) red[w] = m;
    __syncthreads();
    m = fmaxf(fmaxf(red[0], red[1]), fmaxf(red[2], red[3]));
    floatx4 e;
#pragma unroll
    for (int j = 0; j < 4; j++) e[j] = __expf(v[j] - m);
    float s = e[0] + e[1] + e[2] + e[3];
#pragma unroll
    for (int o = 1; o < 64; o <<= 1) s += __shfl_xor(s, o);
    if (lane == 0) red[4 + w] = s;
    __syncthreads();
    s = red[4] + red[5] + red[6] + red[7];
    float inv = 1.0f / s;
    half4 o4;
#pragma unroll
    for (int j = 0; j < 4; j++) o4[j] = (half_t)(e[j] * inv);
    ((half4*)(wt + row * 1024))[t] = o4;
}

extern "C" void kernel_launch(void* const* d_in, const int* in_sizes, int n_in,
                              void* d_out, int out_size, void* d_ws, size_t ws_size,
                              hipStream_t stream)
{
    const float* src = (const float*)d_in[0];   // (S=1024, B=32, 1024)
    const float* tgt = (const float*)d_in[1];   // (T=1024, B=32, 1024)
    const float* W1  = (const float*)d_in[2];   // (A=1024, 1024)
    const float* W2  = (const float*)d_in[3];
    float* out = (float*)d_out;                 // (T, B, 1024)

    char* ws = (char*)d_ws;
    const size_t MB = 1024ull * 1024ull;
    half_t* srcH  = (half_t*)(ws);              // 64MB (S,B,D) fp16
    half_t* tgtH  = (half_t*)(ws + 64  * MB);   // 64MB (T,B,D) fp16
    half_t* tsH   = (half_t*)(ws + 128 * MB);   // 64MB (S,B,A) fp16
    half_t* ttH   = (half_t*)(ws + 192 * MB);   // 64MB (T,B,A) fp16
    half_t* srcT  = (half_t*)(ws + 256 * MB);   // 64MB (B,D,S) fp16
    float*  scores= (float*) (ws + 320 * MB);   // 128MB (B,T,S) fp32
    half_t* w1h   = (half_t*)(ws + 448 * MB);   // 2MB
    half_t* w2h   = (half_t*)(ws + 450 * MB);   // 2MB
    half_t* wts   = srcH;                       // weights reuse srcH (dead after proj1)

    // prep: fp32 -> fp16 (+ transposed source)
    cvt_f16<<<32768, 256, 0, stream>>>(tgt, tgtH, 8388608);
    cvt_f16<<<1024, 256, 0, stream>>>(W1, w1h, 262144);
    cvt_f16<<<1024, 256, 0, stream>>>(W2, w2h, 262144);
    transpose_src_f16<<<dim3(32, 32, 32), 256, 0, stream>>>(src, srcT, srcH);

    // projections: ts = src*W1^T, tt = tgt*W2^T  (M=32768, N=1024, K=1024)
    gemm256<true><<<512, 512, 0, stream>>>(srcH, w1h, tsH,
        1024, 1024, 1024, 1024, 0ll, 0ll, 0ll, 4, 128);
    gemm256<true><<<512, 512, 0, stream>>>(tgtH, w2h, ttH,
        1024, 1024, 1024, 1024, 0ll, 0ll, 0ll, 4, 128);

    // scores[b][t][s] = sum_a tt[t,b,a]*ts[s,b,a]  (batched over b)
    gemm256<false><<<512, 512, 0, stream>>>(ttH, tsH, scores,
        32768, 32768, 1024, 1024, 1024ll, 1024ll, 1024ll * 1024ll, 4, 4);

    // softmax over s
    softmax_k<<<32768, 256, 0, stream>>>(scores, wts);

    // out[t][b][d] = sum_s wts[b][t][s] * srcT[b][d][s]
    gemm256<false><<<512, 512, 0, stream>>>(wts, srcT, out,
        1024, 1024, 32768, 1024, 1024ll * 1024ll, 1024ll * 1024ll, 1024ll, 4, 4);
}

// Round 5
// 632.425 us; speedup vs baseline: 1.9176x; 1.1085x over previous
//
#include <hip/hip_runtime.h>
#include <hip/hip_bf16.h>

typedef _Float16 half_t;
typedef __attribute__((ext_vector_type(8))) _Float16 half8;
typedef __attribute__((ext_vector_type(4))) _Float16 half4;
typedef __attribute__((ext_vector_type(4))) float floatx4;
typedef __attribute__((ext_vector_type(4))) float f32x4;

#define DEVFN static __device__ __forceinline__

// async global->LDS, 16B per lane; lds dest must be wave-uniform base
DEVFN void gll16(const void* g, void* l) {
    __builtin_amdgcn_global_load_lds(
        (const __attribute__((address_space(1))) unsigned int*)g,
        (__attribute__((address_space(3))) unsigned int*)l, 16, 0, 0);
}
DEVFN f32x4 mfma16(half8 a, half8 b, f32x4 c) {
    return __builtin_amdgcn_mfma_f32_16x16x32_f16(a, b, c, 0, 0, 0);
}
DEVFN void vm0() { asm volatile("s_waitcnt vmcnt(0)" ::: "memory"); __builtin_amdgcn_sched_barrier(0); }
DEVFN void vm4() { asm volatile("s_waitcnt vmcnt(4)" ::: "memory"); __builtin_amdgcn_sched_barrier(0); }
DEVFN void bar() { __builtin_amdgcn_s_barrier(); __builtin_amdgcn_sched_barrier(0); }

// ---------------- prep: fp32 -> fp16 ----------------
__global__ __launch_bounds__(256) void cvt_f16(
    const float* __restrict__ in, half_t* __restrict__ out, int n4)
{
    int i = blockIdx.x * 256 + threadIdx.x;
    if (i >= n4) return;
    floatx4 v = ((const floatx4*)in)[i];
    half4 h;
#pragma unroll
    for (int j = 0; j < 4; j++) h[j] = (half_t)v[j];
    ((half4*)out)[i] = h;
}

// ---------------- prep: W (A,D) f32 -> Wt (D,A) f16 ----------------
__global__ __launch_bounds__(256) void transpose_w(
    const float* __restrict__ w, half_t* __restrict__ wt)
{
    __shared__ float tile[32][33];
    int a0 = blockIdx.x << 5, d0 = blockIdx.y << 5;
    int t = threadIdx.x;
    int ai = t >> 3, dj = (t & 7) << 2;
    floatx4 v = *(const floatx4*)&w[(size_t)(a0 + ai) * 1024 + d0 + dj];
    tile[ai][dj + 0] = v[0]; tile[ai][dj + 1] = v[1];
    tile[ai][dj + 2] = v[2]; tile[ai][dj + 3] = v[3];
    __syncthreads();
    int di = t >> 3, aj = (t & 7) << 2;
    half4 o;
#pragma unroll
    for (int q = 0; q < 4; q++) o[q] = (half_t)tile[aj + q][di];
    *(half4*)&wt[(size_t)(d0 + di) * 1024 + a0 + aj] = o;
}

// ---------------- prep: srcT[b][d][s] + srcH[s][b][d] = fp16(source) ----------------
__global__ __launch_bounds__(256) void transpose_src_f16(
    const float* __restrict__ src, half_t* __restrict__ srcT, half_t* __restrict__ srcH)
{
    __shared__ float tile[32][33];
    int s0 = blockIdx.x << 5, d0 = blockIdx.y << 5, b = blockIdx.z;
    int t = threadIdx.x;
    int si = t >> 3, dj = (t & 7) << 2;
    floatx4 v = *(const floatx4*)&src[((size_t)(s0 + si) * 32 + b) * 1024 + d0 + dj];
    tile[si][dj + 0] = v[0]; tile[si][dj + 1] = v[1];
    tile[si][dj + 2] = v[2]; tile[si][dj + 3] = v[3];
    half4 hv;
#pragma unroll
    for (int j = 0; j < 4; j++) hv[j] = (half_t)v[j];
    *(half4*)&srcH[((size_t)(s0 + si) * 32 + b) * 1024 + d0 + dj] = hv;
    __syncthreads();
    int di = t >> 3, sj = (t & 7) << 2;
    half4 o;
#pragma unroll
    for (int q = 0; q < 4; q++) o[q] = (half_t)tile[sj + q][di];
    *(half4*)&srcT[((size_t)b * 1024 + d0 + di) * 1024 + s0 + sj] = o;
}

// ---------------- fp16 GEMM: 256x256 tile, BK=64, 8 waves, dbuf LDS, ----------------
// overlap schedule: 2 barriers + 2 counted vmcnt per K-tile, issue-early ds_reads.
// C(MxN) = A(MxK)*B(NxK)^T, batched; 1-D grid w/ XCD swizzle (nwg%8==0).
template <bool OUT_F16>
__global__ __launch_bounds__(512, 2) void gemm256(
    const half_t* __restrict__ A, const half_t* __restrict__ B,
    void* __restrict__ Cv,
    int lda, int ldb, int ldc, int K,
    long long bA, long long bB, long long bC,
    int gx, int gy)
{
    __shared__ char lds[131072];
    // A: buf*32768 + kh*16384 (256 rows x 32 halfs = 64B rows); B: +65536
    const int nwg = gridDim.x;
    const int bid = blockIdx.x;
    const int sw = (bid & 7) * (nwg >> 3) + (bid >> 3);
    const int x = sw % gx;
    const int r1 = sw / gx;
    const int y = r1 % gy;
    const int z = r1 / gy;

    const int t = threadIdx.x, lane = t & 63, w = t >> 6;
    const int wr = w >> 2, wc = w & 3;           // wave tile: rows wr*128..+128, cols wc*64..+64
    const int m0 = y << 8, n0 = x << 8;
    const half_t* pA = A + (size_t)bA * z + (size_t)m0 * lda;
    const half_t* pB = B + (size_t)bB * z + (size_t)n0 * ldb;

    // staging: per K-half (256 rows x 32 halfs = 16KB), 1024 slots of 16B, 2/thread
    int srow[2], scol[2];
#pragma unroll
    for (int i = 0; i < 2; i++) {
        int slot = (w << 7) + (i << 6) + lane;
        srow[i] = slot >> 2;
        scol[i] = (slot & 3) << 3;
    }
    const unsigned stOff = (unsigned)((w << 7) << 4);   // wave-uniform byte base

    const int lr = lane & 15, q = lane >> 4;
    const unsigned aRd = (unsigned)((((wr << 7) + lr) << 6) + (q << 4));           // + m*1024
    const unsigned bRd = 65536u + (unsigned)((((wc << 6) + lr) << 6) + (q << 4));  // + n*1024

    f32x4 acc[8][4];
#pragma unroll
    for (int m = 0; m < 8; m++)
#pragma unroll
        for (int n = 0; n < 4; n++) acc[m][n] = (f32x4){0.f, 0.f, 0.f, 0.f};

    auto stA = [&](int nb, int kh, int kc) {
#pragma unroll
        for (int i = 0; i < 2; i++)
            gll16(pA + (size_t)srow[i] * lda + (kc + kh * 32 + scol[i]),
                  lds + (nb << 15) + (kh << 14) + stOff + (i << 10));
    };
    auto stB = [&](int nb, int kh, int kc) {
#pragma unroll
        for (int i = 0; i < 2; i++)
            gll16(pB + (size_t)srow[i] * ldb + (kc + kh * 32 + scol[i]),
                  lds + 65536 + (nb << 15) + (kh << 14) + stOff + (i << 10));
    };

    // prologue: stage tile 0 into buf0 in order L1=A-kh0, L2=B-kh0, L3=A-kh1, L4=B-kh1
    stA(0, 0, 0); stB(0, 0, 0); stA(0, 1, 0); stB(0, 1, 0);

    half8 av_a[4], av_b[4], bv0[4], bv1[4];
    const int NT = K >> 6;
    for (int tt = 0; tt < NT; ++tt) {
        const int buf = tt & 1, nb = buf ^ 1;
        const bool st = (tt + 1 < NT);
        const int kn = (tt + 1) << 6;
        const unsigned b0 = (unsigned)(buf << 15);
        const unsigned b1 = b0 + 16384u;

        // ---- B0: publish kh0(t); all reads of nb finished last tile ----
        vm4();                      // drain L1,L2(t); L3,L4(t) stay in flight
        bar();
        if (st) stA(nb, 0, kn);     // L1(t+1)
        // kh0 reads, issue-early: av_a(m0-3), bv0(n0-3), av_b(m4-7)
#pragma unroll
        for (int m = 0; m < 4; m++) av_a[m] = *(const half8*)(lds + b0 + aRd + m * 1024);
#pragma unroll
        for (int n = 0; n < 4; n++) bv0[n] = *(const half8*)(lds + b0 + bRd + n * 1024);
#pragma unroll
        for (int m = 0; m < 4; m++) av_b[m] = *(const half8*)(lds + b0 + aRd + (4 + m) * 1024);
        __builtin_amdgcn_s_setprio(1);
#pragma unroll
        for (int m = 0; m < 4; m++)
#pragma unroll
            for (int n = 0; n < 4; n++)
                acc[m][n] = mfma16(av_a[m], bv0[n], acc[m][n]);   // MFMA_A (av_b still flying)
        __builtin_amdgcn_s_setprio(0);
        if (st) stB(nb, 0, kn);     // L2(t+1)

        // ---- BM: publish kh1(t) ----
        if (st) vm4(); else vm0();  // drain L3,L4(t)
        bar();
        // kh1 reads fly under MFMA_B
#pragma unroll
        for (int m = 0; m < 4; m++) av_a[m] = *(const half8*)(lds + b1 + aRd + m * 1024);
#pragma unroll
        for (int n = 0; n < 4; n++) bv1[n] = *(const half8*)(lds + b1 + bRd + n * 1024);
        __builtin_amdgcn_s_setprio(1);
#pragma unroll
        for (int m = 0; m < 4; m++)
#pragma unroll
            for (int n = 0; n < 4; n++)
                acc[4 + m][n] = mfma16(av_b[m], bv0[n], acc[4 + m][n]);  // MFMA_B
        __builtin_amdgcn_s_setprio(0);
        if (st) stA(nb, 1, kn);     // L3(t+1)
#pragma unroll
        for (int m = 0; m < 4; m++) av_b[m] = *(const half8*)(lds + b1 + aRd + (4 + m) * 1024);
        __builtin_amdgcn_s_setprio(1);
#pragma unroll
        for (int m = 0; m < 4; m++)
#pragma unroll
            for (int n = 0; n < 4; n++)
                acc[m][n] = mfma16(av_a[m], bv1[n], acc[m][n]);          // MFMA_C
        __builtin_amdgcn_s_setprio(0);
        if (st) stB(nb, 1, kn);     // L4(t+1)
        __builtin_amdgcn_s_setprio(1);
#pragma unroll
        for (int m = 0; m < 4; m++)
#pragma unroll
            for (int n = 0; n < 4; n++)
                acc[4 + m][n] = mfma16(av_b[m], bv1[n], acc[4 + m][n]);  // MFMA_D
        __builtin_amdgcn_s_setprio(0);
    }

    // ---- epilogue ----
    const size_t zC = (size_t)bC * z;
    const int r0 = m0 + (wr << 7) + (q << 2);
    const int c0 = n0 + (wc << 6) + lr;
#pragma unroll
    for (int m = 0; m < 8; m++)
#pragma unroll
        for (int fn = 0; fn < 4; fn++)
#pragma unroll
            for (int j = 0; j < 4; j++) {
                size_t idx = zC + (size_t)(r0 + m * 16 + j) * ldc + (c0 + fn * 16);
                if constexpr (OUT_F16)
                    ((half_t*)Cv)[idx] = (half_t)acc[m][fn][j];
                else
                    ((float*)Cv)[idx] = acc[m][fn][j];
            }
}

// ---------------- in-place row softmax on fp16 scores: wt[b][t][s] = softmax_s ----------------
__global__ __launch_bounds__(256) void softmax_h(half_t* __restrict__ sc)
{
    size_t row = blockIdx.x;
    half_t* p = sc + row * 1024;
    int t = threadIdx.x, lane = t & 63, w = t >> 6;
    half4 v4 = ((const half4*)p)[t];
    float v[4];
#pragma unroll
    for (int j = 0; j < 4; j++) v[j] = (float)v4[j];
    float m = fmaxf(fmaxf(v[0], v[1]), fmaxf(v[2], v[3]));
#pragma unroll
    for (int o = 1; o < 64; o <<= 1) m = fmaxf(m, __shfl_xor(m, o));
    __shared__ float red[8];
    if (lane == 0) red[w] = m;
    __syncthreads();
    m = fmaxf(fmaxf(red[0], red[1]), fmaxf(red[2], red[3]));
    float e[4];
#pragma unroll
    for (int j = 0; j < 4; j++) e[j] = __expf(v[j] - m);
    float s = e[0] + e[1] + e[2] + e[3];
#pragma unroll
    for (int o = 1; o < 64; o <<= 1) s += __shfl_xor(s, o);
    if (lane == 0) red[4 + w] = s;
    __syncthreads();
    s = red[4] + red[5] + red[6] + red[7];
    float inv = 1.0f / s;
    half4 o4;
#pragma unroll
    for (int j = 0; j < 4; j++) o4[j] = (half_t)(e[j] * inv);
    ((half4*)p)[t] = o4;
}

extern "C" void kernel_launch(void* const* d_in, const int* in_sizes, int n_in,
                              void* d_out, int out_size, void* d_ws, size_t ws_size,
                              hipStream_t stream)
{
    const float* src = (const float*)d_in[0];   // (S=1024, B=32, 1024)
    const float* tgt = (const float*)d_in[1];   // (T=1024, B=32, 1024)
    const float* W1  = (const float*)d_in[2];   // (A=1024, 1024)
    const float* W2  = (const float*)d_in[3];
    float* out = (float*)d_out;                 // (T, B, 1024)

    char* ws = (char*)d_ws;
    const size_t MB = 1024ull * 1024ull;
    half_t* srcH    = (half_t*)(ws);             // 64MB (S,B,D) fp16
    half_t* tgtH    = (half_t*)(ws + 64  * MB);  // 64MB (T,B,D) fp16
    half_t* uH      = (half_t*)(ws + 128 * MB);  // 64MB (T,B,D1) fp16: u = tgt·G^T
    half_t* srcT    = (half_t*)(ws + 192 * MB);  // 64MB (B,D,S) fp16
    half_t* scoresH = (half_t*)(ws + 256 * MB);  // 64MB (B,T,S) fp16 (softmax in-place)
    half_t* w1t     = (half_t*)(ws + 320 * MB);  // 2MB (D,A) fp16
    half_t* w2t     = (half_t*)(ws + 322 * MB);  // 2MB (D,A) fp16
    half_t* G       = (half_t*)(ws + 324 * MB);  // 2MB (D1,D2) fp16: G = W1^T·W2

    // prep
    transpose_w<<<dim3(32, 32), 256, 0, stream>>>(W1, w1t);
    transpose_w<<<dim3(32, 32), 256, 0, stream>>>(W2, w2t);
    cvt_f16<<<32768, 256, 0, stream>>>(tgt, tgtH, 8388608);
    transpose_src_f16<<<dim3(32, 32, 32), 256, 0, stream>>>(src, srcT, srcH);

    // G[d1,d2] = sum_a W1[a,d1]*W2[a,d2]  (M=N=K=1024)
    gemm256<true><<<16, 512, 0, stream>>>(w1t, w2t, G,
        1024, 1024, 1024, 1024, 0ll, 0ll, 0ll, 4, 4);

    // u[tb,d1] = sum_d2 tgt[tb,d2]*G[d1,d2]  (M=32768, N=1024, K=1024)
    gemm256<true><<<512, 512, 0, stream>>>(tgtH, G, uH,
        1024, 1024, 1024, 1024, 0ll, 0ll, 0ll, 4, 128);

    // scores[b][t][s] = sum_d1 u[t,b,d1]*src[s,b,d1]  (batched over b, fp16 out)
    gemm256<true><<<512, 512, 0, stream>>>(uH, srcH, scoresH,
        32768, 32768, 1024, 1024, 1024ll, 1024ll, 1024ll * 1024ll, 4, 4);

    // softmax over s (in place)
    softmax_h<<<32768, 256, 0, stream>>>(scoresH);

    // out[t][b][d] = sum_s wts[b][t][s]*srcT[b][d][s]
    gemm256<false><<<512, 512, 0, stream>>>(scoresH, srcT, out,
        1024, 1024, 32768, 1024, 1024ll * 1024ll, 1024ll * 1024ll, 1024ll, 4, 4);
}